// Round 12
// baseline (621.018 us; speedup 1.0000x reference)
//
#include <hip/hip_runtime.h>
#include <math.h>

#define NND 50000
#define NED 800000
#define NGR 2048
#define NT  1024          // rad-table entries (uniform in xe = exp(-d))
#define NB  512           // fine bins
#define NPB 98            // nodes per bin (512*98 = 50176 >= NND)
#define NFSTR 145         // LDS nf row stride (odd -> atomics spread all 32 banks)
#define BCAP 2048         // bin capacity (mean 1568, +12 sigma)
#define LCAP 24           // per-block LDS bin capacity (mean 8)
#define LSTR 25
#define BIN_BLOCKS 196    // ceil(NED / 4096)
#define TBL_BLOCKS 2      // 2 blocks x 512 lanes = NT entries

// exp(-5) and derived RBF constants, computed in double then rounded once.
constexpr double dSTART = 0.006737946999085467;
constexpr float  K_START = (float)dSTART;
constexpr float  K_STEP  = (float)((1.0 - dSTART) / 127.0);
constexpr float  K_BETA  = (float)(1.0 / ((2.0/128.0*(1.0-dSTART)) * (2.0/128.0*(1.0-dSTART))));
constexpr float  K_TSTEP = (float)((1.0 - dSTART) / (double)(NT - 1));
constexpr float  K_INVT  = (float)((double)(NT - 1) / (1.0 - dSTART));

__device__ __forceinline__ float silu_f(float x) {
    return x * __builtin_amdgcn_rcpf(1.0f + __expf(-x));
}

// ---------------- phase 1: LDS-multisplit binning || rad-table build ----------------
// Bin blocks (196 x 1024): 4096 edges each, split into 512 bins in LDS, flush
// each bin's run with ONE global reservation (contiguous writes). Record packs
// src(16b)<<7 | dst_local(7b). Table blocks (2 x 512 active lanes) tabulate
// rad(xe) and zero out[]. LDS is aliased between the two paths (union-style).
__global__ void __launch_bounds__(1024)
bin_table(const int* __restrict__ esrc, const int* __restrict__ edst,
          int* __restrict__ bincnt, unsigned* __restrict__ bins,
          const float* __restrict__ W1, const float* __restrict__ b1,
          const float* __restrict__ W2, const float* __restrict__ b2,
          const float* __restrict__ W3, float* __restrict__ table,
          float* __restrict__ out)
{
    __shared__ unsigned smem[NB + NB * LSTR];    // 53,248 B; table path aliases as float hb
    const int bid = blockIdx.x;
    const int tid = threadIdx.x;

    if (bid < BIN_BLOCKS) {
        int*      lcnt = (int*)smem;
        unsigned* lbuf = smem + NB;
        if (tid < NB) lcnt[tid] = 0;
        __syncthreads();
        const int e0 = bid * 4096;
        #pragma unroll
        for (int r = 0; r < 4; ++r) {
            int e = e0 + r * 1024 + tid;
            if (e < NED) {
                int dst = edst[e];
                int src = esrc[e];
                int b = dst / NPB;                       // const divide -> magic mul
                unsigned rec = ((unsigned)src << 7) | (unsigned)(dst - b * NPB);
                int p = atomicAdd(&lcnt[b], 1);
                if (p < LCAP) lbuf[b * LSTR + p] = rec;
                else {                                   // rare overflow: direct append
                    int gp = atomicAdd(&bincnt[b], 1);
                    if (gp < BCAP) bins[b * BCAP + gp] = rec;
                }
            }
        }
        __syncthreads();
        if (tid < NB) {
            int c = lcnt[tid]; c = c < LCAP ? c : LCAP;
            if (c > 0) {
                int base = atomicAdd(&bincnt[tid], c);
                for (int i = 0; i < c; ++i)
                    if (base + i < BCAP) bins[tid * BCAP + base + i] = lbuf[tid * LSTR + i];
            }
        }
        return;
    }

    // ---- table path: 2 blocks, lanes tid<512 active; also zero out[2048] ----
    const int tb = bid - BIN_BLOCKS;                    // 0..1
    out[tb * 1024 + tid] = 0.0f;
    if (tid >= 512) return;
    const int ti = tb * 512 + tid;                      // 0..1023
    const int l  = tid & 63;
    float* hb = (float*)smem + (tid >> 6) * (64 * 17);  // per-wave [64][17], 34.8 KB total

    const float xe = K_START + K_TSTEP * (float)ti;
    const float dd = -logf(xe);
    const float cutv = (dd < 5.0f) ? (0.5f * (__cosf(dd * 0.6283185307179586f) + 1.0f)) : 0.0f;

    // layer 1: h1[j] = b1[j] + sum_k rbf[k] * W1[k][j]
    float h1[64];
    {
        const float4* bp = (const float4*)b1;
        #pragma unroll
        for (int j4 = 0; j4 < 16; ++j4) {
            float4 b = bp[j4];
            h1[4*j4+0] = b.x; h1[4*j4+1] = b.y; h1[4*j4+2] = b.z; h1[4*j4+3] = b.w;
        }
    }
    #pragma unroll 2
    for (int k = 0; k < 128; ++k) {
        float mean = K_START + K_STEP * (float)k;
        float t = xe - mean;
        float rk = cutv * __expf(-K_BETA * t * t);
        const float4* wr = (const float4*)(W1 + (k << 6));
        #pragma unroll
        for (int j4 = 0; j4 < 16; ++j4) {
            float4 wv = wr[j4];
            h1[4*j4+0] = fmaf(rk, wv.x, h1[4*j4+0]);
            h1[4*j4+1] = fmaf(rk, wv.y, h1[4*j4+1]);
            h1[4*j4+2] = fmaf(rk, wv.z, h1[4*j4+2]);
            h1[4*j4+3] = fmaf(rk, wv.w, h1[4*j4+3]);
        }
    }

    // layer 2 (chunked LDS for runtime-k activation reads)
    float h2[64];
    {
        const float4* bp = (const float4*)b2;
        #pragma unroll
        for (int j4 = 0; j4 < 16; ++j4) {
            float4 b = bp[j4];
            h2[4*j4+0] = b.x; h2[4*j4+1] = b.y; h2[4*j4+2] = b.z; h2[4*j4+3] = b.w;
        }
    }
    #pragma unroll
    for (int ch = 0; ch < 4; ++ch) {
        #pragma unroll
        for (int j = 0; j < 16; ++j) hb[l*17 + j] = silu_f(h1[ch*16 + j]);
        for (int k = 0; k < 16; ++k) {
            float hk = hb[l*17 + k];
            const float4* wr = (const float4*)(W2 + ((ch*16 + k) << 6));
            #pragma unroll
            for (int j4 = 0; j4 < 16; ++j4) {
                float4 wv = wr[j4];
                h2[4*j4+0] = fmaf(hk, wv.x, h2[4*j4+0]);
                h2[4*j4+1] = fmaf(hk, wv.y, h2[4*j4+1]);
                h2[4*j4+2] = fmaf(hk, wv.z, h2[4*j4+2]);
                h2[4*j4+3] = fmaf(hk, wv.w, h2[4*j4+3]);
            }
        }
    }

    // layer 3
    float rad[16];
    #pragma unroll
    for (int cc = 0; cc < 16; ++cc) rad[cc] = 0.0f;
    #pragma unroll
    for (int ch = 0; ch < 4; ++ch) {
        #pragma unroll
        for (int j = 0; j < 16; ++j) hb[l*17 + j] = silu_f(h2[ch*16 + j]);
        for (int k = 0; k < 16; ++k) {
            float hk = hb[l*17 + k];
            const float4* wr = (const float4*)(W3 + ((ch*16 + k) << 4));
            #pragma unroll
            for (int c4 = 0; c4 < 4; ++c4) {
                float4 wv = wr[c4];
                rad[4*c4+0] = fmaf(hk, wv.x, rad[4*c4+0]);
                rad[4*c4+1] = fmaf(hk, wv.y, rad[4*c4+1]);
                rad[4*c4+2] = fmaf(hk, wv.z, rad[4*c4+2]);
                rad[4*c4+3] = fmaf(hk, wv.w, rad[4*c4+3]);
            }
        }
    }

    float4* rp = (float4*)(table + (size_t)ti * 16);
    rp[0] = make_float4(rad[0],  rad[1],  rad[2],  rad[3]);
    rp[1] = make_float4(rad[4],  rad[5],  rad[6],  rad[7]);
    rp[2] = make_float4(rad[8],  rad[9],  rad[10], rad[11]);
    rp[3] = make_float4(rad[12], rad[13], rad[14], rad[15]);
}

// ---------------- phase 2: LDS-atomic aggregation + head, one block per bin ----------------
// nf[98][145] lives in LDS (56.8 KB). Edge phase: each thread takes one bin
// record, computes geometry inline (pos is L2-hot), lerps rad[16], and does
// 144 ds_add_f32 into its node's row (stride 145 -> all 32 banks, <=2-way).
// Dead edges (d>=5) skipped: contribute exactly the reference's zero. Then
// fix-up (nf*isd + atom_table) and the head runs straight from LDS.
// No geo buffer, no per-node scatter, no HBM round-trip.
__global__ void __launch_bounds__(1024)
agg_head(const float* __restrict__ pos,
         const int* __restrict__ bincnt, const unsigned* __restrict__ bins,
         const float* __restrict__ table,
         const float* __restrict__ atom_table, const int* __restrict__ node_atom,
         const int* __restrict__ batch,
         const float* __restrict__ Wh1, const float* __restrict__ bh1,
         const float* __restrict__ Wh2, const float* __restrict__ bh2,
         float* __restrict__ out, float isd, float isn)
{
    __shared__ float nf[NPB * NFSTR];          // 56,840 B
    const int b   = blockIdx.x;
    const int tid = threadIdx.x;
    const int base_node = b * NPB;

    for (int i = tid; i < NPB * NFSTR; i += 1024) nf[i] = 0.0f;
    __syncthreads();

    int nb = bincnt[b]; nb = nb < BCAP ? nb : BCAP;

    for (int i = tid; i < nb; i += 1024) {
        unsigned rec = bins[b * BCAP + i];
        int src   = (int)(rec >> 7);
        int local = (int)(rec & 127u);
        int dst   = base_node + local;
        float vx = pos[3*src+0] - pos[3*dst+0];
        float vy = pos[3*src+1] - pos[3*dst+1];
        float vz = pos[3*src+2] - pos[3*dst+2];
        float d2 = vx*vx + vy*vy + vz*vz;
        if (d2 >= 25.0f) continue;             // dead edge: exact zero contribution

        float ddv = sqrtf(d2);
        float inv = 1.0f / fmaxf(ddv, 1e-12f);
        float ux = vx*inv, uy = vy*inv, uz = vz*inv;
        float xe = __expf(-ddv);

        float t = (xe - K_START) * K_INVT;
        int i0 = (int)t;
        i0 = i0 < 0 ? 0 : (i0 > NT-2 ? NT-2 : i0);
        float fr = t - (float)i0;
        const float* tb0 = table + (size_t)i0 * 16;
        const float* tb1 = tb0 + 16;

        float sh[9];
        sh[0] = 1.0f;
        sh[1] = 1.7320508075688772f * ux;
        sh[2] = 1.7320508075688772f * uy;
        sh[3] = 1.7320508075688772f * uz;
        sh[4] = 3.872983346207417f * ux * uz;
        sh[5] = 3.872983346207417f * ux * uy;
        sh[6] = 2.23606797749979f * (uy*uy - 0.5f*(ux*ux + uz*uz));
        sh[7] = 3.872983346207417f * uy * uz;
        sh[8] = 1.9364916731037085f * (uz*uz - ux*ux);

        float* nrow = nf + local * NFSTR;
        #pragma unroll
        for (int c = 0; c < 16; ++c) {
            float rc = fmaf(fr, tb1[c] - tb0[c], tb0[c]);
            #pragma unroll
            for (int s = 0; s < 9; ++s)
                atomicAdd(&nrow[c*9 + s], rc * sh[s]);   // ds_add_f32
        }
    }
    __syncthreads();

    // fix-up: nf = nf*isd + atom_table[node_atom[n]]
    for (int i = tid; i < NPB * 144; i += 1024) {
        int n = i / 144, k = i - n * 144;
        int gn = base_node + n;
        if (gn < NND) {
            int a = node_atom[gn];
            nf[n * NFSTR + k] = fmaf(nf[n * NFSTR + k], isd, atom_table[(size_t)a * 144 + k]);
        }
    }
    __syncthreads();

    // head: wave w handles local nodes [w*8, w*8+8) (w < 13; 13*8=104 covers 98)
    const int lane = tid & 63;
    const int w    = tid >> 6;
    if (w >= 13) return;
    const int g0 = w * 8;

    float A0[8], A1[8], A2[8];
    {
        float bb0 = bh1[lane], bb1 = bh1[lane + 64];
        float bb2 = (lane < 16) ? bh1[lane + 128] : 0.0f;
        #pragma unroll
        for (int q = 0; q < 8; ++q) { A0[q] = bb0; A1[q] = bb1; A2[q] = bb2; }
    }

    // clamped row index for OOB q (result discarded by write guard)
    int row[8];
    #pragma unroll
    for (int q = 0; q < 8; ++q) {
        int lq = g0 + q;
        row[q] = (lq < NPB ? lq : 0) * NFSTR;
    }

    for (int k = 0; k < 144; ++k) {
        const float* wr = Wh1 + (size_t)k * 144;
        float w0 = wr[lane];
        float w1 = wr[lane + 64];
        float w2 = (lane < 16) ? wr[lane + 128] : 0.0f;
        #pragma unroll
        for (int q = 0; q < 8; ++q) {
            float nk = nf[row[q] + k];         // LDS broadcast read
            A0[q] = fmaf(nk, w0, A0[q]);
            A1[q] = fmaf(nk, w1, A1[q]);
            A2[q] = fmaf(nk, w2, A2[q]);
        }
    }

    float wl0 = Wh2[lane], wl1 = Wh2[lane + 64];
    float wl2 = (lane < 16) ? Wh2[lane + 128] : 0.0f;
    float bv  = bh2[0];
    #pragma unroll
    for (int q = 0; q < 8; ++q) {
        float en = silu_f(A0[q]) * wl0 + silu_f(A1[q]) * wl1;
        if (lane < 16) en = fmaf(silu_f(A2[q]), wl2, en);
        en += __shfl_down(en, 32);
        en += __shfl_down(en, 16);
        en += __shfl_down(en, 8);
        en += __shfl_down(en, 4);
        en += __shfl_down(en, 2);
        en += __shfl_down(en, 1);
        int lq = g0 + q;
        int gn = base_node + lq;
        if (lane == 0 && lq < NPB && gn < NND) {
            unsafeAtomicAdd(out + batch[gn], (en + bv) * isn);
        }
    }
}

extern "C" void kernel_launch(void* const* d_in, const int* in_sizes, int n_in,
                              void* d_out, int out_size, void* d_ws, size_t ws_size,
                              hipStream_t stream) {
    const float* pos        = (const float*)d_in[0];
    const float* atom_table = (const float*)d_in[1];
    const float* W1         = (const float*)d_in[2];
    const float* b1         = (const float*)d_in[3];
    const float* W2         = (const float*)d_in[4];
    const float* b2         = (const float*)d_in[5];
    const float* W3         = (const float*)d_in[6];
    const float* Wh1        = (const float*)d_in[7];
    const float* bh1        = (const float*)d_in[8];
    const float* Wh2        = (const float*)d_in[9];
    const float* bh2        = (const float*)d_in[10];
    const int*   node_atom  = (const int*)d_in[11];
    const int*   edge_src   = (const int*)d_in[12];
    const int*   edge_dst   = (const int*)d_in[13];
    const int*   batch      = (const int*)d_in[14];

    float* out = (float*)d_out;

    // workspace layout
    char*     wsb    = (char*)d_ws;
    int*      bincnt = (int*)(wsb);                  // [NB]        2048 B
    float*    table  = (float*)(wsb + 2048);         // [NT][16]    65536 B (16B-al)
    unsigned* bins   = (unsigned*)(wsb + 67584);     // [NB][BCAP]  4 MB

    hipMemsetAsync(bincnt, 0, NB * 4, stream);

    bin_table<<<BIN_BLOCKS + TBL_BLOCKS, 1024, 0, stream>>>(
        edge_src, edge_dst, bincnt, bins, W1, b1, W2, b2, W3, table, out);

    float isd = 1.0f / sqrtf(15.57930850982666f);
    float isn = 1.0f / sqrtf(18.03065905448718f);
    agg_head<<<NB, 1024, 0, stream>>>(
        pos, bincnt, bins, table, atom_table, node_atom, batch,
        Wh1, bh1, Wh2, bh2, out, isd, isn);
}

// Round 13
// 239.522 us; speedup vs baseline: 2.5927x; 2.5927x over previous
//
#include <hip/hip_runtime.h>
#include <math.h>

#define NND 50000
#define NED 800000
#define NGR 2048
#define NT  1024          // rad-table entries (uniform in xe = exp(-d))
#define NB  512           // bins of NPB nodes
#define NPB 98
#define HALF 49           // nodes per agg block (half-bin)
#define BCAP 2048         // bin record capacity (mean 1562, +12 sigma)
#define SCAP 1152         // sorted-geo LDS capacity per half-bin (mean 781, +13 sigma)
#define LCAP 24           // bin_table per-block LDS bin capacity (mean 8)
#define LSTR 25
#define BIN_BLOCKS 196    // ceil(NED / 4096)
#define TBL_BLOCKS 2      // 2 blocks x 512 lanes = NT entries

// exp(-5) and derived RBF constants, computed in double then rounded once.
constexpr double dSTART = 0.006737946999085467;
constexpr float  K_START = (float)dSTART;
constexpr float  K_STEP  = (float)((1.0 - dSTART) / 127.0);
constexpr float  K_BETA  = (float)(1.0 / ((2.0/128.0*(1.0-dSTART)) * (2.0/128.0*(1.0-dSTART))));
constexpr float  K_TSTEP = (float)((1.0 - dSTART) / (double)(NT - 1));
constexpr float  K_INVT  = (float)((double)(NT - 1) / (1.0 - dSTART));

__device__ __forceinline__ float silu_f(float x) {
    return x * __builtin_amdgcn_rcpf(1.0f + __expf(-x));
}

// ---------------- phase 1: LDS-multisplit binning || rad-table build ----------------
// (unchanged from round 12 — bin part measured fine; the regression was agg_head)
__global__ void __launch_bounds__(1024)
bin_table(const int* __restrict__ esrc, const int* __restrict__ edst,
          int* __restrict__ bincnt, unsigned* __restrict__ bins,
          const float* __restrict__ W1, const float* __restrict__ b1,
          const float* __restrict__ W2, const float* __restrict__ b2,
          const float* __restrict__ W3, float* __restrict__ table,
          float* __restrict__ out)
{
    __shared__ unsigned smem[NB + NB * LSTR];    // 53,248 B; table path aliases as float hb
    const int bid = blockIdx.x;
    const int tid = threadIdx.x;

    if (bid < BIN_BLOCKS) {
        int*      lcnt = (int*)smem;
        unsigned* lbuf = smem + NB;
        if (tid < NB) lcnt[tid] = 0;
        __syncthreads();
        const int e0 = bid * 4096;
        #pragma unroll
        for (int r = 0; r < 4; ++r) {
            int e = e0 + r * 1024 + tid;
            if (e < NED) {
                int dst = edst[e];
                int src = esrc[e];
                int b = dst / NPB;                       // const divide -> magic mul
                unsigned rec = ((unsigned)src << 7) | (unsigned)(dst - b * NPB);
                int p = atomicAdd(&lcnt[b], 1);
                if (p < LCAP) lbuf[b * LSTR + p] = rec;
                else {                                   // rare overflow: direct append
                    int gp = atomicAdd(&bincnt[b], 1);
                    if (gp < BCAP) bins[b * BCAP + gp] = rec;
                }
            }
        }
        __syncthreads();
        if (tid < NB) {
            int c = lcnt[tid]; c = c < LCAP ? c : LCAP;
            if (c > 0) {
                int base = atomicAdd(&bincnt[tid], c);
                for (int i = 0; i < c; ++i)
                    if (base + i < BCAP) bins[tid * BCAP + base + i] = lbuf[tid * LSTR + i];
            }
        }
        return;
    }

    // ---- table path: 2 blocks, lanes tid<512 active; also zero out[2048] ----
    const int tb = bid - BIN_BLOCKS;                    // 0..1
    out[tb * 1024 + tid] = 0.0f;
    if (tid >= 512) return;
    const int ti = tb * 512 + tid;                      // 0..1023
    const int l  = tid & 63;
    float* hb = (float*)smem + (tid >> 6) * (64 * 17);

    const float xe = K_START + K_TSTEP * (float)ti;
    const float dd = -logf(xe);
    const float cutv = (dd < 5.0f) ? (0.5f * (__cosf(dd * 0.6283185307179586f) + 1.0f)) : 0.0f;

    float h1[64];
    {
        const float4* bp = (const float4*)b1;
        #pragma unroll
        for (int j4 = 0; j4 < 16; ++j4) {
            float4 b = bp[j4];
            h1[4*j4+0] = b.x; h1[4*j4+1] = b.y; h1[4*j4+2] = b.z; h1[4*j4+3] = b.w;
        }
    }
    #pragma unroll 2
    for (int k = 0; k < 128; ++k) {
        float mean = K_START + K_STEP * (float)k;
        float t = xe - mean;
        float rk = cutv * __expf(-K_BETA * t * t);
        const float4* wr = (const float4*)(W1 + (k << 6));
        #pragma unroll
        for (int j4 = 0; j4 < 16; ++j4) {
            float4 wv = wr[j4];
            h1[4*j4+0] = fmaf(rk, wv.x, h1[4*j4+0]);
            h1[4*j4+1] = fmaf(rk, wv.y, h1[4*j4+1]);
            h1[4*j4+2] = fmaf(rk, wv.z, h1[4*j4+2]);
            h1[4*j4+3] = fmaf(rk, wv.w, h1[4*j4+3]);
        }
    }

    float h2[64];
    {
        const float4* bp = (const float4*)b2;
        #pragma unroll
        for (int j4 = 0; j4 < 16; ++j4) {
            float4 b = bp[j4];
            h2[4*j4+0] = b.x; h2[4*j4+1] = b.y; h2[4*j4+2] = b.z; h2[4*j4+3] = b.w;
        }
    }
    #pragma unroll
    for (int ch = 0; ch < 4; ++ch) {
        #pragma unroll
        for (int j = 0; j < 16; ++j) hb[l*17 + j] = silu_f(h1[ch*16 + j]);
        for (int k = 0; k < 16; ++k) {
            float hk = hb[l*17 + k];
            const float4* wr = (const float4*)(W2 + ((ch*16 + k) << 6));
            #pragma unroll
            for (int j4 = 0; j4 < 16; ++j4) {
                float4 wv = wr[j4];
                h2[4*j4+0] = fmaf(hk, wv.x, h2[4*j4+0]);
                h2[4*j4+1] = fmaf(hk, wv.y, h2[4*j4+1]);
                h2[4*j4+2] = fmaf(hk, wv.z, h2[4*j4+2]);
                h2[4*j4+3] = fmaf(hk, wv.w, h2[4*j4+3]);
            }
        }
    }

    float rad[16];
    #pragma unroll
    for (int cc = 0; cc < 16; ++cc) rad[cc] = 0.0f;
    #pragma unroll
    for (int ch = 0; ch < 4; ++ch) {
        #pragma unroll
        for (int j = 0; j < 16; ++j) hb[l*17 + j] = silu_f(h2[ch*16 + j]);
        for (int k = 0; k < 16; ++k) {
            float hk = hb[l*17 + k];
            const float4* wr = (const float4*)(W3 + ((ch*16 + k) << 4));
            #pragma unroll
            for (int c4 = 0; c4 < 4; ++c4) {
                float4 wv = wr[c4];
                rad[4*c4+0] = fmaf(hk, wv.x, rad[4*c4+0]);
                rad[4*c4+1] = fmaf(hk, wv.y, rad[4*c4+1]);
                rad[4*c4+2] = fmaf(hk, wv.z, rad[4*c4+2]);
                rad[4*c4+3] = fmaf(hk, wv.w, rad[4*c4+3]);
            }
        }
    }

    float4* rp = (float4*)(table + (size_t)ti * 16);
    rp[0] = make_float4(rad[0],  rad[1],  rad[2],  rad[3]);
    rp[1] = make_float4(rad[4],  rad[5],  rad[6],  rad[7]);
    rp[2] = make_float4(rad[8],  rad[9],  rad[10], rad[11]);
    rp[3] = make_float4(rad[12], rad[13], rad[14], rad[15]);
}

// ---------------- phase 2: in-LDS counting sort + register aggregation + head ----------------
// One block per HALF-bin (49 nodes). Pass A: count this half's records (LDS
// atomics on 49 counters only). Wave-scan. Pass B: geometry thread-parallel,
// scatter float4 geo into sorted LDS (dead edges -> (0,0,0,K_START) sentinel
// -> lerp hits table[0]==0 -> exact zero, as rounds 10-11). Aggregation:
// round-10 structure — 8-lane group streams its node's sorted records from
// LDS (broadcast b128 reads), accumulates in REGISTERS (no atomics). Head
// unchanged. Replaces the 95us geo HBM scatter + 91us agg kernel.
__global__ void __launch_bounds__(448)
agg_head(const float* __restrict__ pos,
         const int* __restrict__ bincnt, const unsigned* __restrict__ bins,
         const float* __restrict__ table,
         const float* __restrict__ atom_table, const int* __restrict__ node_atom,
         const int* __restrict__ batch,
         const float* __restrict__ Wh1, const float* __restrict__ bh1,
         const float* __restrict__ Wh2, const float* __restrict__ bh2,
         float* __restrict__ out, float isd, float isn)
{
    __shared__ int    lcnt[HALF], soff[HALF], scur[HALF];
    __shared__ float4 sgeo[SCAP];                  // 18,432 B
    __shared__ float  nf_s[7][8][144];             // 32,256 B
    const int tid = threadIdx.x;
    const int b   = blockIdx.x >> 1;
    const int h   = blockIdx.x & 1;
    const int lbase = h * HALF;
    const int gbase = b * NPB + lbase;

    if (tid < HALF) lcnt[tid] = 0;
    __syncthreads();

    int nrec = bincnt[b]; nrec = nrec < BCAP ? nrec : BCAP;
    const unsigned* myb = bins + b * BCAP;

    // ---- pass A: count this half's records ----
    for (int i = tid; i < nrec; i += 448) {
        int l = (int)(myb[i] & 127u) - lbase;
        if (l >= 0 && l < HALF) atomicAdd(&lcnt[l], 1);
    }
    __syncthreads();

    // ---- exclusive scan over 49 counters (wave 0) ----
    if (tid < 64) {
        int v = (tid < HALF) ? lcnt[tid] : 0;
        int x = v;
        #pragma unroll
        for (int off = 1; off < 64; off <<= 1) {
            int u = __shfl_up(x, off);
            if (tid >= off) x += u;
        }
        if (tid < HALF) { soff[tid] = x - v; scur[tid] = x - v; }
    }
    __syncthreads();

    // ---- pass B: geometry + scatter into sorted LDS ----
    for (int i = tid; i < nrec; i += 448) {
        unsigned rec = myb[i];
        int local = (int)(rec & 127u);
        int l = local - lbase;
        if (l < 0 || l >= HALF) continue;
        int src = (int)(rec >> 7);
        int dst = b * NPB + local;
        float vx = pos[3*src+0] - pos[3*dst+0];
        float vy = pos[3*src+1] - pos[3*dst+1];
        float vz = pos[3*src+2] - pos[3*dst+2];
        float d2 = vx*vx + vy*vy + vz*vz;
        float4 g;
        if (d2 < 25.0f) {
            float ddv = sqrtf(d2);
            float inv = 1.0f / fmaxf(ddv, 1e-12f);
            g = make_float4(vx*inv, vy*inv, vz*inv, __expf(-ddv));
        } else {
            g = make_float4(0.0f, 0.0f, 0.0f, K_START);   // exact-zero sentinel
        }
        int p = atomicAdd(&scur[l], 1);
        if (p < SCAP) sgeo[p] = g;
    }
    __syncthreads();

    // ---- aggregation: wave w, group g -> node slot l = w*8+g ----
    const int lane = tid & 63;
    const int w    = tid >> 6;           // 0..6
    const int g    = lane >> 3;
    const int c    = lane & 7;           // channels c and c+8
    const int l    = w * 8 + g;          // 0..55, valid < HALF
    const int gn   = gbase + l;
    const bool valid = (l < HALF) && (gn < NND);

    float acc0[9], acc1[9];
    #pragma unroll
    for (int s = 0; s < 9; ++s) { acc0[s] = 0.0f; acc1[s] = 0.0f; }

    int start = 0, end = 0;
    if (valid) {
        start = soff[l];
        end   = start + lcnt[l];
        end   = end < SCAP ? end : SCAP;
    }

    for (int p = start; p < end; ++p) {
        float4 gv = sgeo[p];             // all 8 group lanes same addr -> broadcast
        float ux = gv.x, uy = gv.y, uz = gv.z, xe = gv.w;

        float t = (xe - K_START) * K_INVT;
        int i0 = (int)t;
        i0 = i0 < 0 ? 0 : (i0 > NT-2 ? NT-2 : i0);
        float fr = t - (float)i0;
        const float* tb = table + (size_t)i0 * 16 + c;
        float r0a = tb[0], r1a = tb[16];
        float r0b = tb[8], r1b = tb[24];
        float ra = fmaf(fr, r1a - r0a, r0a);
        float rb = fmaf(fr, r1b - r0b, r0b);

        float sh1 = 1.7320508075688772f * ux;
        float sh2 = 1.7320508075688772f * uy;
        float sh3 = 1.7320508075688772f * uz;
        float sh4 = 3.872983346207417f * ux * uz;
        float sh5 = 3.872983346207417f * ux * uy;
        float sh6 = 2.23606797749979f * (uy*uy - 0.5f*(ux*ux + uz*uz));
        float sh7 = 3.872983346207417f * uy * uz;
        float sh8 = 1.9364916731037085f * (uz*uz - ux*ux);

        acc0[0] += ra;                    acc1[0] += rb;
        acc0[1] = fmaf(ra, sh1, acc0[1]); acc1[1] = fmaf(rb, sh1, acc1[1]);
        acc0[2] = fmaf(ra, sh2, acc0[2]); acc1[2] = fmaf(rb, sh2, acc1[2]);
        acc0[3] = fmaf(ra, sh3, acc0[3]); acc1[3] = fmaf(rb, sh3, acc1[3]);
        acc0[4] = fmaf(ra, sh4, acc0[4]); acc1[4] = fmaf(rb, sh4, acc1[4]);
        acc0[5] = fmaf(ra, sh5, acc0[5]); acc1[5] = fmaf(rb, sh5, acc1[5]);
        acc0[6] = fmaf(ra, sh6, acc0[6]); acc1[6] = fmaf(rb, sh6, acc1[6]);
        acc0[7] = fmaf(ra, sh7, acc0[7]); acc1[7] = fmaf(rb, sh7, acc1[7]);
        acc0[8] = fmaf(ra, sh8, acc0[8]); acc1[8] = fmaf(rb, sh8, acc1[8]);
    }

    // nf = atom_table[atom] + deg_embed * isd -> this wave's LDS slab
    {
        int a = valid ? node_atom[gn] : 0;
        const float* at = atom_table + (size_t)a * 144;
        #pragma unroll
        for (int s = 0; s < 9; ++s) {
            nf_s[w][g][c*9 + s]     = fmaf(acc0[s], isd, at[c*9 + s]);
            nf_s[w][g][(c+8)*9 + s] = fmaf(acc1[s], isd, at[(c+8)*9 + s]);
        }
    }
    // same-wave LDS write->read: hardware-ordered, no barrier

    // ---- head: hn = silu(nf @ Wh1 + bh1); energy = hn @ Wh2 + bh2 ----
    float A0[8], A1[8], A2[8];
    {
        float bb0 = bh1[lane], bb1 = bh1[lane + 64];
        float bb2 = (lane < 16) ? bh1[lane + 128] : 0.0f;
        #pragma unroll
        for (int q = 0; q < 8; ++q) { A0[q] = bb0; A1[q] = bb1; A2[q] = bb2; }
    }

    for (int k4 = 0; k4 < 36; ++k4) {
        float4 nq[8];
        #pragma unroll
        for (int q = 0; q < 8; ++q)
            nq[q] = *(const float4*)&nf_s[w][q][k4*4];      // LDS broadcast
        const float* wrow = Wh1 + (size_t)(k4*4) * 144;     // L2-hot global
#define HSTEP(COMP, OFF) { \
        float w0 = wrow[(OFF)*144 + lane]; \
        float w1 = wrow[(OFF)*144 + lane + 64]; \
        float w2 = (lane < 16) ? wrow[(OFF)*144 + lane + 128] : 0.0f; \
        _Pragma("unroll") \
        for (int q = 0; q < 8; ++q) { \
            float nk = nq[q].COMP; \
            A0[q] = fmaf(nk, w0, A0[q]); \
            A1[q] = fmaf(nk, w1, A1[q]); \
            A2[q] = fmaf(nk, w2, A2[q]); } }
        HSTEP(x, 0) HSTEP(y, 1) HSTEP(z, 2) HSTEP(w, 3)
#undef HSTEP
    }

    float wl0 = Wh2[lane], wl1 = Wh2[lane + 64];
    float wl2 = (lane < 16) ? Wh2[lane + 128] : 0.0f;
    float bv  = bh2[0];
    #pragma unroll
    for (int q = 0; q < 8; ++q) {
        float en = silu_f(A0[q]) * wl0 + silu_f(A1[q]) * wl1;
        if (lane < 16) en = fmaf(silu_f(A2[q]), wl2, en);
        en += __shfl_down(en, 32);
        en += __shfl_down(en, 16);
        en += __shfl_down(en, 8);
        en += __shfl_down(en, 4);
        en += __shfl_down(en, 2);
        en += __shfl_down(en, 1);
        int lq = w * 8 + q;
        int gq = gbase + lq;
        if (lane == 0 && lq < HALF && gq < NND) {
            unsafeAtomicAdd(out + batch[gq], (en + bv) * isn);
        }
    }
}

extern "C" void kernel_launch(void* const* d_in, const int* in_sizes, int n_in,
                              void* d_out, int out_size, void* d_ws, size_t ws_size,
                              hipStream_t stream) {
    const float* pos        = (const float*)d_in[0];
    const float* atom_table = (const float*)d_in[1];
    const float* W1         = (const float*)d_in[2];
    const float* b1         = (const float*)d_in[3];
    const float* W2         = (const float*)d_in[4];
    const float* b2         = (const float*)d_in[5];
    const float* W3         = (const float*)d_in[6];
    const float* Wh1        = (const float*)d_in[7];
    const float* bh1        = (const float*)d_in[8];
    const float* Wh2        = (const float*)d_in[9];
    const float* bh2        = (const float*)d_in[10];
    const int*   node_atom  = (const int*)d_in[11];
    const int*   edge_src   = (const int*)d_in[12];
    const int*   edge_dst   = (const int*)d_in[13];
    const int*   batch      = (const int*)d_in[14];

    float* out = (float*)d_out;

    // workspace layout
    char*     wsb    = (char*)d_ws;
    int*      bincnt = (int*)(wsb);                  // [NB]        2048 B
    float*    table  = (float*)(wsb + 2048);         // [NT][16]    65536 B (16B-al)
    unsigned* bins   = (unsigned*)(wsb + 67584);     // [NB][BCAP]  4 MB

    hipMemsetAsync(bincnt, 0, NB * 4, stream);

    bin_table<<<BIN_BLOCKS + TBL_BLOCKS, 1024, 0, stream>>>(
        edge_src, edge_dst, bincnt, bins, W1, b1, W2, b2, W3, table, out);

    float isd = 1.0f / sqrtf(15.57930850982666f);
    float isn = 1.0f / sqrtf(18.03065905448718f);
    agg_head<<<NB * 2, 448, 0, stream>>>(
        pos, bincnt, bins, table, atom_table, node_atom, batch,
        Wh1, bh1, Wh2, bh2, out, isd, isn);
}